// Round 9
// baseline (147.540 us; speedup 1.0000x reference)
//
#include <hip/hip_runtime.h>

// Problem constants (fixed by setup_inputs): B=4096, D=512, H=W=64, N=4096.
#define B_ROWS 4096
#define N_COLS 4096
#define DIM    512
#define LDK    1024   // row stride (elements) of split bf16 arrays [hi(512) | lo(512)]

typedef __attribute__((ext_vector_type(8))) short short8;
typedef __attribute__((ext_vector_type(4))) float floatx4;

// bf16 round-to-nearest-even split helpers (bit-exact, no API dependence)
__device__ __forceinline__ unsigned short f2bf_rn(float f) {
    unsigned u = __float_as_uint(f);
    u += 0x7fffu + ((u >> 16) & 1u);
    return (unsigned short)(u >> 16);
}
__device__ __forceinline__ float bf2f(unsigned short h) {
    return __uint_as_float(((unsigned)h) << 16);
}

// Monotone float->uint map; (key<<32)|idx gives u64 atomicMin argmin with
// smallest-index tie-break (matches numpy argmin semantics).
__device__ __forceinline__ unsigned long long pack_key(float v, int idx) {
    unsigned u = __float_as_uint(v);
    u = (u & 0x80000000u) ? ~u : (u | 0x80000000u);
    return ((unsigned long long)u << 32) | (unsigned)idx;
}

// Async global->LDS, 16B per lane. LDS dest is wave-uniform base + lane*16;
// global source address IS per-lane (m173).
__device__ __forceinline__ void async16(const unsigned short* g, unsigned short* l) {
    __builtin_amdgcn_global_load_lds(
        (__attribute__((address_space(1))) void*)g,
        (__attribute__((address_space(3))) void*)l, 16, 0, 0);
}

// One wave per row (4 rows/block): split fp32 row into bf16 hi/lo halves,
// compute exact fp32 ||row||^2, init packed argmin accumulators. (v7 verbatim)
__global__ __launch_bounds__(256) void som_convert(
    const float* __restrict__ X, const float* __restrict__ Wt,
    unsigned short* __restrict__ Xc, unsigned short* __restrict__ Wc,
    float* __restrict__ x_sq, float* __restrict__ w_sq,
    unsigned long long* __restrict__ packed)
{
    int wave = threadIdx.x >> 6, lane = threadIdx.x & 63;
    int grow = blockIdx.x * 4 + wave;            // 0..8191
    bool isX = grow < B_ROWS;
    const float* src = isX ? (X + (size_t)grow * DIM)
                           : (Wt + (size_t)(grow - B_ROWS) * DIM);
    const float4* p4 = (const float4*)src;
    float4 a = p4[lane * 2], b = p4[lane * 2 + 1];
    float f[8] = {a.x, a.y, a.z, a.w, b.x, b.y, b.z, b.w};
    short8 hi, lo;
    float s = 0.f;
    #pragma unroll
    for (int t = 0; t < 8; ++t) {
        unsigned short h = f2bf_rn(f[t]);
        hi[t] = (short)h;
        lo[t] = (short)f2bf_rn(f[t] - bf2f(h));
        s = fmaf(f[t], f[t], s);
    }
    unsigned short* dst = (isX ? Xc + (size_t)grow * LDK
                               : Wc + (size_t)(grow - B_ROWS) * LDK) + lane * 8;
    *(short8*)(dst)       = hi;
    *(short8*)(dst + 512) = lo;
    #pragma unroll
    for (int off = 32; off >= 1; off >>= 1) s += __shfl_xor(s, off, 64);
    if (lane == 0) {
        if (isX) { x_sq[grow] = s; packed[grow] = ~0ull; }
        else     { w_sq[grow - B_ROWS] = s; }
    }
}

// ---------------------------------------------------------------------------
// Split-bf16 distance GEMM v10: FRAGMENT-INTENSITY fix. Nine prior structures
// all pinned at MfmaUtil 30-36% because a 64x64 wave tile needs 16KB operand
// fragments per 48 MFMAs (~21 B/cyc/wave) -- above the ~85 B/cyc LDS port at
// any occupancy. v10 uses a 128x128 wave tile (acc 8x8): 32KB per 192 MFMAs
// = 10.6 B/cyc/wave; 4 waves => 42 B/cyc/CU, UNDER the port. MFMA becomes
// the binding resource (per step per SIMD: 192 MFMA ~ 3100 cyc vs LDS 1500).
//   - block 256x256, 4 waves 2x2, 128x128/wave, BK=32, grid 16x16 = 1/CU
//   - 128KB double-buffered LDS; v8's proven counted-gate schedule scaled:
//     gate vmcnt(16) [kt+1's 16 loads in flight] -> barrier -> read hi ->
//     64 MFMA -> read lo -> lgkm0+barrier -> stage kt+2 -> 128 MFMA
//     (stage cover ~128 MFMA + full next step >> HBM latency)
//   - v7's granule-rotation subtile layout: coalesced 64B-segment staging,
//     2-way (free) fragment reads
// Per-acc product order identical to v1 (hh, ah*bl, al*bh; k ascending)
// => bit-exact.
// LDS map per buffer (shorts): A subtile (rsub,h) at (rsub*2+h)*512,
// rsub=0..15; B at +16384. Buffers at 0 / 32768.
// ---------------------------------------------------------------------------
#define MFMA64(AF, BF)                                          \
    _Pragma("unroll")                                           \
    for (int i = 0; i < 8; ++i)                                 \
        _Pragma("unroll")                                       \
        for (int j = 0; j < 8; ++j)                             \
            acc[i][j] = __builtin_amdgcn_mfma_f32_16x16x32_bf16( \
                AF[i], BF[j], acc[i][j], 0, 0, 0);

__global__ __launch_bounds__(256, 1) void som_dist_v10(
    const unsigned short* __restrict__ Xc, const unsigned short* __restrict__ Wc,
    const float* __restrict__ w_sq, unsigned long long* __restrict__ packed)
{
    __shared__ __align__(16) unsigned short L[2 * 32768];   // 128 KiB
    const int tid  = threadIdx.x;
    const int wave = tid >> 6, lane = tid & 63;
    const int quad = lane >> 4, t16 = lane & 15;
    const int wr = wave >> 1, wc = wave & 1;       // 2x2 wave grid, 128x128/wave
    const int bm = blockIdx.y, bn = blockIdx.x;

    // Staging: wave stages A rows [wave*64, +64) and B rows [wave*64, +64),
    // 16 async16/K-step (4 subtiles x 2 halves x {A,B}), rotation-coalesced.
    const int srow = lane >> 2;                            // 0..15
    const int scol = ((((lane & 3) - ((lane >> 3) & 3)) & 3)) * 8;
    const unsigned short* gA = Xc + (size_t)(bm * 256 + wave * 64 + srow) * LDK + scol;
    const unsigned short* gB = Wc + (size_t)(bn * 256 + wave * 64 + srow) * LDK + scol;
    const int wofsA = wave * 8 * 512;            // A subtiles wave*4..+3
    const int wofsB = 16384 + wave * 8 * 512;    // B subtiles wave*4..+3

    // Fragment read offset: word within subtile for (row t16, chunk quad).
    const int rdw8 = (4 * t16 + ((quad + ((t16 >> 1) & 3)) & 3)) * 8;
    const unsigned short* const pAb = &L[wr * 8192 + rdw8];          // +i*1024+h*512
    const unsigned short* const pBb = &L[16384 + wc * 8192 + rdw8];  // +j*1024+h*512

    floatx4 acc[8][8];
    #pragma unroll
    for (int i = 0; i < 8; ++i)
        #pragma unroll
        for (int j = 0; j < 8; ++j) acc[i][j] = (floatx4){0.f, 0.f, 0.f, 0.f};

    // Prologue: stage tile 0 -> buf0, tile 1 -> buf1 (32 loads in flight).
    #pragma unroll
    for (int b = 0; b < 2; ++b) {
        unsigned short* base = &L[b * 32768];
        const int k0 = b * 32;
        #pragma unroll
        for (int q = 0; q < 4; ++q) {
            async16(gA + k0 + q * 16 * LDK,       base + wofsA + q * 1024);
            async16(gA + k0 + q * 16 * LDK + 512, base + wofsA + q * 1024 + 512);
            async16(gB + k0 + q * 16 * LDK,       base + wofsB + q * 1024);
            async16(gB + k0 + q * 16 * LDK + 512, base + wofsB + q * 1024 + 512);
        }
    }

    #pragma unroll 1
    for (int kt = 0; kt < 16; ++kt) {
        const int cur = kt & 1;

        // GATE: this wave's tile-kt loads retired (kt+1's 16 stay in flight).
        if (kt == 15) asm volatile("s_waitcnt vmcnt(0)" ::: "memory");
        else          asm volatile("s_waitcnt vmcnt(16)" ::: "memory");
        __builtin_amdgcn_s_barrier();

        const unsigned short* pA = pAb + cur * 32768;
        const unsigned short* pB = pBb + cur * 32768;
        short8 ah[8], bh[8], bl[8], al[8];
        #pragma unroll
        for (int i = 0; i < 8; ++i) ah[i] = *(const short8*)(pA + i * 1024);
        #pragma unroll
        for (int j = 0; j < 8; ++j) bh[j] = *(const short8*)(pB + j * 1024);

        __builtin_amdgcn_s_setprio(1);
        MFMA64(ah, bh)
        __builtin_amdgcn_s_setprio(0);

        #pragma unroll
        for (int j = 0; j < 8; ++j) bl[j] = *(const short8*)(pB + j * 1024 + 512);
        #pragma unroll
        for (int i = 0; i < 8; ++i) al[i] = *(const short8*)(pA + i * 1024 + 512);

        // READ-DONE: all reads of buf[cur] retired in regs; after barrier,
        // tile kt+2 may overwrite buf[cur] while clusters 2-3 compute.
        asm volatile("s_waitcnt lgkmcnt(0)" ::: "memory");
        __builtin_amdgcn_s_barrier();

        if (kt < 14) {
            unsigned short* base = &L[cur * 32768];
            const int k0 = (kt + 2) * 32;
            #pragma unroll
            for (int q = 0; q < 4; ++q) {
                async16(gA + k0 + q * 16 * LDK,       base + wofsA + q * 1024);
                async16(gA + k0 + q * 16 * LDK + 512, base + wofsA + q * 1024 + 512);
                async16(gB + k0 + q * 16 * LDK,       base + wofsB + q * 1024);
                async16(gB + k0 + q * 16 * LDK + 512, base + wofsB + q * 1024 + 512);
            }
        }

        __builtin_amdgcn_s_setprio(1);
        MFMA64(ah, bl)
        MFMA64(al, bh)
        __builtin_amdgcn_s_setprio(0);
    }

    // Epilogue: val = w_sq - 2*dot (x_sq is per-row constant, irrelevant to
    // argmin). C/D layout: col = t16, row = quad*4 + reg  [m89/m91].
    const int col0 = bn * 256 + wc * 128 + t16;
    float wq[8];
    #pragma unroll
    for (int j = 0; j < 8; ++j) wq[j] = w_sq[col0 + j * 16];
    const int row_base = bm * 256 + wr * 128 + quad * 4;
    #pragma unroll
    for (int i = 0; i < 8; ++i) {
        #pragma unroll
        for (int r = 0; r < 4; ++r) {
            unsigned long long best = ~0ull;
            #pragma unroll
            for (int j = 0; j < 8; ++j) {
                float val = fmaf(-2.f, acc[i][j][r], wq[j]);
                unsigned long long key = pack_key(val, col0 + j * 16);
                best = (key < best) ? key : best;
            }
            #pragma unroll
            for (int m = 1; m <= 8; m <<= 1) {     // reduce 16-lane col group
                unsigned long long o = __shfl_xor(best, m, 64);
                best = (o < best) ? o : best;
            }
            if (t16 == 0)
                atomicMin(&packed[row_base + i * 16 + r], best);
        }
    }
}

// Unpack argmin, qe = sqrt(max(||x||^2 + val, 0)).
// d_out: bmu_indices (4096 x 2) flat, then qe (4096), all float. (unchanged)
__global__ __launch_bounds__(256) void som_finalize(
    const unsigned long long* __restrict__ packed,
    const float* __restrict__ x_sq, float* __restrict__ out)
{
    int b = blockIdx.x * 256 + threadIdx.x;  // 0..4095
    unsigned long long p = packed[b];
    unsigned idx = (unsigned)(p & 0xffffffffull);
    unsigned key = (unsigned)(p >> 32);
    unsigned u = (key & 0x80000000u) ? (key & 0x7fffffffu) : ~key;
    float val = __uint_as_float(u);
    float sq = fmaxf(x_sq[b] + val, 0.f);
    out[2 * b]     = (float)(idx >> 6);   // y = idx / 64
    out[2 * b + 1] = (float)(idx & 63);   // x = idx % 64
    out[2 * B_ROWS + b] = sqrtf(sq);
}

extern "C" void kernel_launch(void* const* d_in, const int* in_sizes, int n_in,
                              void* d_out, int out_size, void* d_ws, size_t ws_size,
                              hipStream_t stream) {
    const float* X  = (const float*)d_in[0];   // (4096, 512)
    const float* Wt = (const float*)d_in[1];   // (64, 64, 512) -> (4096, 512)
    float* out = (float*)d_out;

    // ws layout: [0,32K) packed u64[4096]; [32K,48K) x_sq; [48K,64K) w_sq;
    // [64K, 64K+8M) Xc bf16 split; [64K+8M, 64K+16M) Wc bf16 split.
    unsigned long long* packed = (unsigned long long*)d_ws;
    float* x_sq = (float*)((char*)d_ws + (32 << 10));
    float* w_sq = (float*)((char*)d_ws + (48 << 10));
    unsigned short* Xc = (unsigned short*)((char*)d_ws + (64 << 10));
    unsigned short* Wc = (unsigned short*)((char*)d_ws + (64 << 10) + ((size_t)B_ROWS * LDK * 2));

    som_convert<<<dim3((B_ROWS + N_COLS) / 4), dim3(256), 0, stream>>>(
        X, Wt, Xc, Wc, x_sq, w_sq, packed);
    som_dist_v10<<<dim3(N_COLS / 256, B_ROWS / 256), dim3(256), 0, stream>>>(
        Xc, Wc, w_sq, packed);
    som_finalize<<<dim3(B_ROWS / 256), dim3(256), 0, stream>>>(packed, x_sq, out);
}

// Round 10
// 116.780 us; speedup vs baseline: 1.2634x; 1.2634x over previous
//
#include <hip/hip_runtime.h>

// Problem constants (fixed by setup_inputs): B=4096, D=512, H=W=64, N=4096.
#define B_ROWS 4096
#define N_COLS 4096
#define DIM    512
#define LDK    1024   // row stride (elements) of split bf16 arrays [hi(512) | lo(512)]

typedef __attribute__((ext_vector_type(8))) short short8;
typedef __attribute__((ext_vector_type(4))) float floatx4;

// bf16 round-to-nearest-even split helpers (bit-exact, no API dependence)
__device__ __forceinline__ unsigned short f2bf_rn(float f) {
    unsigned u = __float_as_uint(f);
    u += 0x7fffu + ((u >> 16) & 1u);
    return (unsigned short)(u >> 16);
}
__device__ __forceinline__ float bf2f(unsigned short h) {
    return __uint_as_float(((unsigned)h) << 16);
}

// Monotone float->uint map; (key<<32)|idx gives u64 atomicMin argmin with
// smallest-index tie-break (matches numpy argmin semantics).
__device__ __forceinline__ unsigned long long pack_key(float v, int idx) {
    unsigned u = __float_as_uint(v);
    u = (u & 0x80000000u) ? ~u : (u | 0x80000000u);
    return ((unsigned long long)u << 32) | (unsigned)idx;
}

// Async global->LDS, 16B per lane. LDS dest is wave-uniform base + lane*16;
// global source address IS per-lane (m173).
__device__ __forceinline__ void async16(const unsigned short* g, unsigned short* l) {
    __builtin_amdgcn_global_load_lds(
        (__attribute__((address_space(1))) void*)g,
        (__attribute__((address_space(3))) void*)l, 16, 0, 0);
}

// One wave per row (4 rows/block): split fp32 row into bf16 hi/lo halves,
// compute exact fp32 ||row||^2, init packed argmin accumulators. (unchanged)
__global__ __launch_bounds__(256) void som_convert(
    const float* __restrict__ X, const float* __restrict__ Wt,
    unsigned short* __restrict__ Xc, unsigned short* __restrict__ Wc,
    float* __restrict__ x_sq, float* __restrict__ w_sq,
    unsigned long long* __restrict__ packed)
{
    int wave = threadIdx.x >> 6, lane = threadIdx.x & 63;
    int grow = blockIdx.x * 4 + wave;            // 0..8191
    bool isX = grow < B_ROWS;
    const float* src = isX ? (X + (size_t)grow * DIM)
                           : (Wt + (size_t)(grow - B_ROWS) * DIM);
    const float4* p4 = (const float4*)src;
    float4 a = p4[lane * 2], b = p4[lane * 2 + 1];
    float f[8] = {a.x, a.y, a.z, a.w, b.x, b.y, b.z, b.w};
    short8 hi, lo;
    float s = 0.f;
    #pragma unroll
    for (int t = 0; t < 8; ++t) {
        unsigned short h = f2bf_rn(f[t]);
        hi[t] = (short)h;
        lo[t] = (short)f2bf_rn(f[t] - bf2f(h));
        s = fmaf(f[t], f[t], s);
    }
    unsigned short* dst = (isX ? Xc + (size_t)grow * LDK
                               : Wc + (size_t)(grow - B_ROWS) * LDK) + lane * 8;
    *(short8*)(dst)       = hi;
    *(short8*)(dst + 512) = lo;
    #pragma unroll
    for (int off = 32; off >= 1; off >>= 1) s += __shfl_xor(s, off, 64);
    if (lane == 0) {
        if (isX) { x_sq[grow] = s; packed[grow] = ~0ull; }
        else     { w_sq[grow - B_ROWS] = s; }
    }
}

// ---------------------------------------------------------------------------
// Split-bf16 distance GEMM v11: m201-shaped 6-phase schedule with ALL
// confounds of v4/v5 removed:
//  - 256x256 block, 8 waves (2x4), 128x64/wave, BK=32, 128KB dbuf
//    (MFMA:LDS cyc ratio 1.24 -> MFMA-bound geometry)
//  - ROTATION-COALESCED cooperative staging (the v4/v5 confound: they used
//    fragment-order staging = 16B global scatter, proven 4x VMEM cost by v6;
//    v7 proved rotation layout = v1-coalesced 64B segments + conflict-free
//    ds_read): all 8 waves stage slices of BOTH A and B
//  - ONE vmcnt(8) gate per K-tile (tile kt+1's 8 loads stay in flight;
//    never drains to 0 until the last tile)
//  - staging issued only after target region's reads are barrier-retired:
//    B(kt+2) at Ph3 (B reads retire at Ph2), A(kt+2) at Ph5 (A reads
//    retire at Ph4) -> no LDS write/read race
//  - NO sched_barrier(0) anywhere (m141: order-pinning defeats scheduler)
//  - phases: {ds-reads; (stage); s_barrier; lgkmcnt(0); setprio(1);
//    16 MFMA; setprio(0); s_barrier}
// LDS (shorts): A-slot0 @0, A-slot1 @16384, B-slot0 @32768, B-slot1 @49152.
// Region image: subtile-unit s = rsub*2+h at s*512 (1KB), rotation layout:
// granule (r,g) at word 4r + ((g + ((r>>1)&3)) & 3)  [v7-verified].
// Per-acc product order identical to v1 (hh, ah*bl, al*bh; k ascending)
// => bit-exact.
// ---------------------------------------------------------------------------
#define MFMA16(AF, BF, I0)                                      \
    _Pragma("unroll")                                           \
    for (int i = 0; i < 4; ++i)                                 \
        _Pragma("unroll")                                       \
        for (int j = 0; j < 4; ++j)                             \
            acc[(I0) + i][j] = __builtin_amdgcn_mfma_f32_16x16x32_bf16( \
                AF[i], BF[j], acc[(I0) + i][j], 0, 0, 0);

#define PH_EXEC(MF)                                             \
    __builtin_amdgcn_s_barrier();                               \
    asm volatile("s_waitcnt lgkmcnt(0)");                       \
    __builtin_amdgcn_s_setprio(1);                              \
    MF                                                          \
    __builtin_amdgcn_s_setprio(0);                              \
    __builtin_amdgcn_s_barrier();

__global__ __launch_bounds__(512, 2) void som_dist_v11(
    const unsigned short* __restrict__ Xc, const unsigned short* __restrict__ Wc,
    const float* __restrict__ w_sq, unsigned long long* __restrict__ packed)
{
    __shared__ __align__(16) unsigned short L[65536];   // 128 KiB
    const int tid  = threadIdx.x;
    const int wave = tid >> 6, lane = tid & 63;
    const int quad = lane >> 4, t16 = lane & 15;
    const int wr = wave >> 2, wc = wave & 3;       // 2x4 wave grid, 128x64/wave
    const int bm = blockIdx.y, bn = blockIdx.x;

    // Cooperative staging: wave stages subtile-units s = wave*4+q (q=0..3)
    // of each region per K-tile (rsub = s>>1, h = s&1; LDS offset s*512).
    // Rotation-coalesced global source (v7): lane l reads row srow=l>>2,
    // chunk ((l&3)-((l>>3)&3))&3 -> 4 lanes = one 64B segment of one row.
    const int srow = lane >> 2;
    const int scol = ((((lane & 3) - ((lane >> 3) & 3)) & 3)) * 8;
    const unsigned short* gAq[4];
    const unsigned short* gBq[4];
    #pragma unroll
    for (int q = 0; q < 4; ++q) {
        const int s = wave * 4 + q, rsub = s >> 1, h = s & 1;
        gAq[q] = Xc + (size_t)(bm * 256 + rsub * 16 + srow) * LDK + h * 512 + scol;
        gBq[q] = Wc + (size_t)(bn * 256 + rsub * 16 + srow) * LDK + h * 512 + scol;
    }

    // Fragment read offset within a subtile-unit (rotation inverse, v7).
    const int rdw8 = (4 * t16 + ((quad + ((t16 >> 1) & 3)) & 3)) * 8;

    floatx4 acc[8][4];
    #pragma unroll
    for (int i = 0; i < 8; ++i)
        #pragma unroll
        for (int j = 0; j < 4; ++j) acc[i][j] = (floatx4){0.f, 0.f, 0.f, 0.f};

    // Prologue: stage tiles 0 and 1 (order per tile: B then A -> per-thread
    // in-flight sequence matches the loop's gate arithmetic). 16 in flight.
    #pragma unroll
    for (int t = 0; t < 2; ++t) {
        const int k0 = t * 32;
        unsigned short* RB = &L[32768 + t * 16384];
        unsigned short* RA = &L[t * 16384];
        #pragma unroll
        for (int q = 0; q < 4; ++q) async16(gBq[q] + k0, RB + (wave * 4 + q) * 512);
        #pragma unroll
        for (int q = 0; q < 4; ++q) async16(gAq[q] + k0, RA + (wave * 4 + q) * 512);
    }

    #pragma unroll 1
    for (int kt = 0; kt < 16; ++kt) {
        const int slot = kt & 1;
        const bool st = (kt < 14);
        const int k2 = (kt + 2) * 32;

        // GATE: own-wave tile-kt loads retired (kt+1's 8 stay in flight);
        // barrier broadcasts -> all waves' slices of kt are in LDS.
        if (kt == 15) asm volatile("s_waitcnt vmcnt(0)");
        else          asm volatile("s_waitcnt vmcnt(8)");
        __builtin_amdgcn_s_barrier();

        const unsigned short* pA = &L[slot * 16384 + wr * 8192 + rdw8];
        const unsigned short* pB = &L[32768 + slot * 16384 + wc * 4096 + rdw8];
        short8 ah0[4], ah1[4], al0[4], al1[4], bh[4], bl[4];

        // Ph1: read ah0, bh; MFMA ah0 x bh
        #pragma unroll
        for (int i = 0; i < 4; ++i) ah0[i] = *(const short8*)(pA + i * 1024);
        #pragma unroll
        for (int j = 0; j < 4; ++j) bh[j]  = *(const short8*)(pB + j * 1024);
        PH_EXEC(MFMA16(ah0, bh, 0))

        // Ph2: read bl; MFMA ah0 x bl   (B reads retire here)
        #pragma unroll
        for (int j = 0; j < 4; ++j) bl[j] = *(const short8*)(pB + j * 1024 + 512);
        PH_EXEC(MFMA16(ah0, bl, 0))

        // Ph3: read al0; stage B(kt+2) into B slot (safe: B reads retired
        // by Ph2's lgkm0 + closing barrier); MFMA al0 x bh
        #pragma unroll
        for (int i = 0; i < 4; ++i) al0[i] = *(const short8*)(pA + i * 1024 + 512);
        if (st) {
            unsigned short* RB = &L[32768 + slot * 16384];
            #pragma unroll
            for (int q = 0; q < 4; ++q) async16(gBq[q] + k2, RB + (wave * 4 + q) * 512);
        }
        PH_EXEC(MFMA16(al0, bh, 0))

        // Ph4: read ah1 + al1 (all remaining A reads); MFMA ah1 x bh
        #pragma unroll
        for (int i = 0; i < 4; ++i) ah1[i] = *(const short8*)(pA + (4 + i) * 1024);
        #pragma unroll
        for (int i = 0; i < 4; ++i) al1[i] = *(const short8*)(pA + (4 + i) * 1024 + 512);
        PH_EXEC(MFMA16(ah1, bh, 4))

        // Ph5: stage A(kt+2) into A slot (safe: A reads retired by Ph4's
        // lgkm0 + closing barrier); MFMA ah1 x bl
        if (st) {
            unsigned short* RA = &L[slot * 16384];
            #pragma unroll
            for (int q = 0; q < 4; ++q) async16(gAq[q] + k2, RA + (wave * 4 + q) * 512);
        }
        PH_EXEC(MFMA16(ah1, bl, 4))

        // Ph6: pure-reg MFMA al1 x bh (gate+barrier of next iter closes it)
        __builtin_amdgcn_s_setprio(1);
        MFMA16(al1, bh, 4)
        __builtin_amdgcn_s_setprio(0);
    }

    // Epilogue: val = w_sq - 2*dot (x_sq is per-row constant, irrelevant to
    // argmin). C/D layout: col = t16, row = quad*4 + reg  [m89/m91].
    const int col0 = bn * 256 + wc * 64 + t16;
    float wq[4];
    #pragma unroll
    for (int j = 0; j < 4; ++j) wq[j] = w_sq[col0 + j * 16];
    const int row_base = bm * 256 + wr * 128 + quad * 4;
    #pragma unroll
    for (int i = 0; i < 8; ++i) {
        #pragma unroll
        for (int r = 0; r < 4; ++r) {
            unsigned long long best = ~0ull;
            #pragma unroll
            for (int j = 0; j < 4; ++j) {
                float val = fmaf(-2.f, acc[i][j][r], wq[j]);
                unsigned long long key = pack_key(val, col0 + j * 16);
                best = (key < best) ? key : best;
            }
            #pragma unroll
            for (int m = 1; m <= 8; m <<= 1) {     // reduce 16-lane col group
                unsigned long long o = __shfl_xor(best, m, 64);
                best = (o < best) ? o : best;
            }
            if (t16 == 0)
                atomicMin(&packed[row_base + i * 16 + r], best);
        }
    }
}

// Unpack argmin, qe = sqrt(max(||x||^2 + val, 0)).
// d_out: bmu_indices (4096 x 2) flat, then qe (4096), all float. (unchanged)
__global__ __launch_bounds__(256) void som_finalize(
    const unsigned long long* __restrict__ packed,
    const float* __restrict__ x_sq, float* __restrict__ out)
{
    int b = blockIdx.x * 256 + threadIdx.x;  // 0..4095
    unsigned long long p = packed[b];
    unsigned idx = (unsigned)(p & 0xffffffffull);
    unsigned key = (unsigned)(p >> 32);
    unsigned u = (key & 0x80000000u) ? (key & 0x7fffffffu) : ~key;
    float val = __uint_as_float(u);
    float sq = fmaxf(x_sq[b] + val, 0.f);
    out[2 * b]     = (float)(idx >> 6);   // y = idx / 64
    out[2 * b + 1] = (float)(idx & 63);   // x = idx % 64
    out[2 * B_ROWS + b] = sqrtf(sq);
}

extern "C" void kernel_launch(void* const* d_in, const int* in_sizes, int n_in,
                              void* d_out, int out_size, void* d_ws, size_t ws_size,
                              hipStream_t stream) {
    const float* X  = (const float*)d_in[0];   // (4096, 512)
    const float* Wt = (const float*)d_in[1];   // (64, 64, 512) -> (4096, 512)
    float* out = (float*)d_out;

    // ws layout: [0,32K) packed u64[4096]; [32K,48K) x_sq; [48K,64K) w_sq;
    // [64K, 64K+8M) Xc bf16 split; [64K+8M, 64K+16M) Wc bf16 split.
    unsigned long long* packed = (unsigned long long*)d_ws;
    float* x_sq = (float*)((char*)d_ws + (32 << 10));
    float* w_sq = (float*)((char*)d_ws + (48 << 10));
    unsigned short* Xc = (unsigned short*)((char*)d_ws + (64 << 10));
    unsigned short* Wc = (unsigned short*)((char*)d_ws + (64 << 10) + ((size_t)B_ROWS * LDK * 2));

    som_convert<<<dim3((B_ROWS + N_COLS) / 4), dim3(256), 0, stream>>>(
        X, Wt, Xc, Wc, x_sq, w_sq, packed);
    som_dist_v11<<<dim3(N_COLS / 256, B_ROWS / 256), dim3(512), 0, stream>>>(
        Xc, Wc, w_sq, packed);
    som_finalize<<<dim3(B_ROWS / 256), dim3(256), 0, stream>>>(packed, x_sq, out);
}